// Round 1
// baseline (325.261 us; speedup 1.0000x reference)
//
#include <hip/hip_runtime.h>

#define NB 8
#define NS 1024
#define ND 1024
#define NH 16
#define NHD 64

typedef __attribute__((ext_vector_type(8))) short bf16x8;
typedef __attribute__((ext_vector_type(4))) float f32x4;

static __device__ __forceinline__ unsigned short f2bf(float f) {
    unsigned int u = __builtin_bit_cast(unsigned int, f);
    unsigned int r = u + 0x7fffu + ((u >> 16) & 1u);
    return (unsigned short)(r >> 16);
}

// ---------------- fp32 -> bf16 convert ----------------
__global__ void cvt_f32_bf16(const float* __restrict__ in, unsigned short* __restrict__ out, int n) {
    int i = (blockIdx.x * blockDim.x + threadIdx.x) * 4;
    if (i >= n) return;
    float4 v = *reinterpret_cast<const float4*>(in + i);
    ushort4 o;
    o.x = f2bf(v.x); o.y = f2bf(v.y); o.z = f2bf(v.z); o.w = f2bf(v.w);
    *reinterpret_cast<ushort4*>(out + i) = o;
}

// ---------------- QKV projection GEMM ----------------
// A: hs_bf [8192][1024] row-major. W (z-selected): [N=1024][K=1024] row-major = B^T.
// out: z=0 Q [B,H,S,HD]; z=1 K [B,H,S,HD]; z=2 V^T [B,H,HD,S]  (all bf16)
__global__ __launch_bounds__(256) void qkv_gemm(
    const unsigned short* __restrict__ A,
    const unsigned short* __restrict__ Wq, const unsigned short* __restrict__ Wk,
    const unsigned short* __restrict__ Wv,
    const float* __restrict__ bq, const float* __restrict__ bk, const float* __restrict__ bv,
    unsigned short* __restrict__ Qo, unsigned short* __restrict__ Ko, unsigned short* __restrict__ Vo)
{
    const int z = blockIdx.z;
    const unsigned short* W = (z == 0) ? Wq : (z == 1) ? Wk : Wv;
    const float* bias = (z == 0) ? bq : (z == 1) ? bk : bv;
    const int m0 = blockIdx.x * 64;
    const int n0 = blockIdx.y * 64;

    __shared__ unsigned short As[64][64];
    __shared__ unsigned short Bs[64][64];

    const int tid = threadIdx.x;
    const int lane = tid & 63;
    const int wave = tid >> 6;

    f32x4 acc[4] = {};

    const int rr = tid >> 3;
    const int c8 = (tid & 7) * 8;
    const int row = wave * 16 + (lane & 15);
    const int kofs = (lane >> 4) * 8;

    for (int kb = 0; kb < ND; kb += 64) {
        *reinterpret_cast<int4*>(&As[rr][c8])      = *reinterpret_cast<const int4*>(&A[(size_t)(m0 + rr) * ND + kb + c8]);
        *reinterpret_cast<int4*>(&As[rr + 32][c8]) = *reinterpret_cast<const int4*>(&A[(size_t)(m0 + rr + 32) * ND + kb + c8]);
        *reinterpret_cast<int4*>(&Bs[rr][c8])      = *reinterpret_cast<const int4*>(&W[(size_t)(n0 + rr) * ND + kb + c8]);
        *reinterpret_cast<int4*>(&Bs[rr + 32][c8]) = *reinterpret_cast<const int4*>(&W[(size_t)(n0 + rr + 32) * ND + kb + c8]);
        __syncthreads();
#pragma unroll
        for (int kk = 0; kk < 2; ++kk) {
            bf16x8 a = *reinterpret_cast<const bf16x8*>(&As[row][kk * 32 + kofs]);
#pragma unroll
            for (int nt = 0; nt < 4; ++nt) {
                bf16x8 b = *reinterpret_cast<const bf16x8*>(&Bs[nt * 16 + (lane & 15)][kk * 32 + kofs]);
                acc[nt] = __builtin_amdgcn_mfma_f32_16x16x32_bf16(a, b, acc[nt], 0, 0, 0);
            }
        }
        __syncthreads();
    }

    // C layout: col = lane&15 (n), row = (lane>>4)*4 + r (m)
#pragma unroll
    for (int nt = 0; nt < 4; ++nt) {
        int n = n0 + nt * 16 + (lane & 15);
        float bv_ = bias[n];
        int h = n >> 6, hd = n & 63;
#pragma unroll
        for (int r2 = 0; r2 < 4; ++r2) {
            int m = m0 + wave * 16 + (lane >> 4) * 4 + r2;
            int b = m >> 10, s = m & 1023;
            unsigned short val = f2bf(acc[nt][r2] + bv_);
            if (z == 0)      Qo[(((size_t)b * NH + h) * NS + s) * NHD + hd] = val;
            else if (z == 1) Ko[(((size_t)b * NH + h) * NS + s) * NHD + hd] = val;
            else             Vo[(((size_t)b * NH + h) * NHD + hd) * NS + s] = val;
        }
    }
}

// ---------------- flash attention with relation bias ----------------
// grid: (S/64, H, B), block 256 (4 waves). Each wave owns 16 q-rows.
__global__ __launch_bounds__(256) void flash_attn(
    const unsigned short* __restrict__ Q, const unsigned short* __restrict__ Kb,
    const unsigned short* __restrict__ Vt,
    const int* __restrict__ rel, const float* __restrict__ rel_emb,
    const float* __restrict__ mask, float* __restrict__ out)
{
    const int q0 = blockIdx.x * 64;
    const int h = blockIdx.y;
    const int b = blockIdx.z;
    const int tid = threadIdx.x, lane = tid & 63, wave = tid >> 6;

    __shared__ unsigned short Ks[64][64];   // [kv][hd]
    __shared__ unsigned short Vs[64][64];   // [hd][kv]  (V^T tile)
    __shared__ unsigned short Ps[4][16][64];
    __shared__ float s_re[8];
    if (tid < 7) s_re[tid] = rel_emb[tid * NH + h];
    __syncthreads();

    const unsigned short* Qh = Q  + (((size_t)b * NH + h) * NS) * NHD;
    const unsigned short* Kh = Kb + (((size_t)b * NH + h) * NS) * NHD;
    const unsigned short* Vh = Vt + (((size_t)b * NH + h) * NHD) * NS;
    const int* relb = rel + (size_t)b * NS * NS;
    const float* maskb = mask + (size_t)b * NS;

    const int kofs = (lane >> 4) * 8;
    const int qrow = q0 + wave * 16 + (lane & 15);
    bf16x8 qa[2];
    qa[0] = *reinterpret_cast<const bf16x8*>(&Qh[(size_t)qrow * NHD + kofs]);
    qa[1] = *reinterpret_cast<const bf16x8*>(&Qh[(size_t)qrow * NHD + 32 + kofs]);

    f32x4 ctx[4] = {};
    float m_run[4], l_run[4];
#pragma unroll
    for (int r = 0; r < 4; ++r) { m_run[r] = -1e30f; l_run[r] = 0.f; }

    const int rr = tid >> 3;
    const int c8 = (tid & 7) * 8;
    const float LOG2E = 1.4426950408889634f;

    for (int kv0 = 0; kv0 < NS; kv0 += 64) {
        *reinterpret_cast<int4*>(&Ks[rr][c8])      = *reinterpret_cast<const int4*>(&Kh[(size_t)(kv0 + rr) * NHD + c8]);
        *reinterpret_cast<int4*>(&Ks[rr + 32][c8]) = *reinterpret_cast<const int4*>(&Kh[(size_t)(kv0 + rr + 32) * NHD + c8]);
        *reinterpret_cast<int4*>(&Vs[rr][c8])      = *reinterpret_cast<const int4*>(&Vh[(size_t)rr * NS + kv0 + c8]);
        *reinterpret_cast<int4*>(&Vs[rr + 32][c8]) = *reinterpret_cast<const int4*>(&Vh[(size_t)(rr + 32) * NS + kv0 + c8]);
        __syncthreads();

        // scores = Q K^T  (C: col=kv local, row=q local)
        f32x4 sc[4] = {};
#pragma unroll
        for (int kk = 0; kk < 2; ++kk) {
#pragma unroll
            for (int nt = 0; nt < 4; ++nt) {
                bf16x8 bfrag = *reinterpret_cast<const bf16x8*>(&Ks[nt * 16 + (lane & 15)][kk * 32 + kofs]);
                sc[nt] = __builtin_amdgcn_mfma_f32_16x16x32_bf16(qa[kk], bfrag, sc[nt], 0, 0, 0);
            }
        }

        // scale + relation bias + mask, track per-row max
        float svals[4][4];
        float pmax[4];
#pragma unroll
        for (int r = 0; r < 4; ++r) pmax[r] = -1e30f;
#pragma unroll
        for (int nt = 0; nt < 4; ++nt) {
            int kvg = kv0 + nt * 16 + (lane & 15);
            float mv = maskb[kvg];
#pragma unroll
            for (int r = 0; r < 4; ++r) {
                int qg = q0 + wave * 16 + (lane >> 4) * 4 + r;
                int rc = relb[(size_t)qg * NS + kvg];
                float sv = sc[nt][r] * 0.125f + s_re[rc] + mv;
                svals[nt][r] = sv;
                pmax[r] = fmaxf(pmax[r], sv);
            }
        }
#pragma unroll
        for (int r = 0; r < 4; ++r) {
            float v = pmax[r];
            v = fmaxf(v, __shfl_xor(v, 1));
            v = fmaxf(v, __shfl_xor(v, 2));
            v = fmaxf(v, __shfl_xor(v, 4));
            v = fmaxf(v, __shfl_xor(v, 8));
            pmax[r] = v;
        }
        float alpha[4], rsum[4];
#pragma unroll
        for (int r = 0; r < 4; ++r) {
            float mnew = fmaxf(m_run[r], pmax[r]);
            alpha[r] = exp2f((m_run[r] - mnew) * LOG2E);
            m_run[r] = mnew;
            rsum[r] = 0.f;
        }
#pragma unroll
        for (int nt = 0; nt < 4; ++nt) {
#pragma unroll
            for (int r = 0; r < 4; ++r) {
                float p = exp2f((svals[nt][r] - m_run[r]) * LOG2E);
                rsum[r] += p;
                Ps[wave][(lane >> 4) * 4 + r][nt * 16 + (lane & 15)] = f2bf(p);
            }
        }
#pragma unroll
        for (int r = 0; r < 4; ++r) {
            float v = rsum[r];
            v += __shfl_xor(v, 1);
            v += __shfl_xor(v, 2);
            v += __shfl_xor(v, 4);
            v += __shfl_xor(v, 8);
            l_run[r] = l_run[r] * alpha[r] + v;
        }
#pragma unroll
        for (int ht = 0; ht < 4; ++ht)
#pragma unroll
            for (int r = 0; r < 4; ++r)
                ctx[ht][r] *= alpha[r];

        // ctx += P V   (A from Ps, B from Vs)
#pragma unroll
        for (int kk = 0; kk < 2; ++kk) {
            bf16x8 pa = *reinterpret_cast<const bf16x8*>(&Ps[wave][lane & 15][kk * 32 + kofs]);
#pragma unroll
            for (int ht = 0; ht < 4; ++ht) {
                bf16x8 bfrag = *reinterpret_cast<const bf16x8*>(&Vs[ht * 16 + (lane & 15)][kk * 32 + kofs]);
                ctx[ht] = __builtin_amdgcn_mfma_f32_16x16x32_bf16(pa, bfrag, ctx[ht], 0, 0, 0);
            }
        }
        __syncthreads();
    }

    // epilogue: out[b][q][h*64+hd] = ctx / l
#pragma unroll
    for (int ht = 0; ht < 4; ++ht) {
        int hd = ht * 16 + (lane & 15);
#pragma unroll
        for (int r = 0; r < 4; ++r) {
            int qg = q0 + wave * 16 + (lane >> 4) * 4 + r;
            out[((size_t)b * NS + qg) * ND + h * NHD + hd] = ctx[ht][r] / l_run[r];
        }
    }
}

extern "C" void kernel_launch(void* const* d_in, const int* in_sizes, int n_in,
                              void* d_out, int out_size, void* d_ws, size_t ws_size,
                              hipStream_t stream) {
    const float* hs      = (const float*)d_in[0];
    const float* mask    = (const float*)d_in[1];
    const int*   rel     = (const int*)d_in[2];
    const float* Wq      = (const float*)d_in[3];
    const float* bq      = (const float*)d_in[4];
    const float* Wk      = (const float*)d_in[5];
    const float* bk      = (const float*)d_in[6];
    const float* Wv      = (const float*)d_in[7];
    const float* bv      = (const float*)d_in[8];
    const float* rel_emb = (const float*)d_in[9];
    float* out = (float*)d_out;

    char* ws = (char*)d_ws;
    unsigned short* q_bf  = (unsigned short*)(ws);                       // 16 MB
    unsigned short* k_bf  = (unsigned short*)(ws + ((size_t)16 << 20));  // 16 MB
    unsigned short* vt_bf = (unsigned short*)(ws + ((size_t)32 << 20));  // 16 MB
    unsigned short* hs_bf = (unsigned short*)(ws + ((size_t)48 << 20));  // 16 MB
    unsigned short* w_bf  = (unsigned short*)(ws + ((size_t)64 << 20));  // 6 MB

    const int nhs = NB * NS * ND;       // 8.4M
    const int nw  = ND * ND;            // 1M
    cvt_f32_bf16<<<nhs / 4 / 256, 256, 0, stream>>>(hs, hs_bf, nhs);
    cvt_f32_bf16<<<nw / 4 / 256, 256, 0, stream>>>(Wq, w_bf, nw);
    cvt_f32_bf16<<<nw / 4 / 256, 256, 0, stream>>>(Wk, w_bf + (size_t)nw, nw);
    cvt_f32_bf16<<<nw / 4 / 256, 256, 0, stream>>>(Wv, w_bf + (size_t)2 * nw, nw);

    qkv_gemm<<<dim3((NB * NS) / 64, ND / 64, 3), 256, 0, stream>>>(
        hs_bf, w_bf, w_bf + (size_t)nw, w_bf + (size_t)2 * nw,
        bq, bk, bv, q_bf, k_bf, vt_bf);

    flash_attn<<<dim3(NS / 64, NH, NB), 256, 0, stream>>>(
        q_bf, k_bf, vt_bf, rel, rel_emb, mask, out);
}

// Round 2
// 228.932 us; speedup vs baseline: 1.4208x; 1.4208x over previous
//
#include <hip/hip_runtime.h>

#define NB 8
#define NS 1024
#define ND 1024
#define NH 16
#define NHD 64

typedef __attribute__((ext_vector_type(8))) short bf16x8;
typedef __attribute__((ext_vector_type(4))) float f32x4;

#define GLOAD_LDS16(g, l) __builtin_amdgcn_global_load_lds(                    \
    (const __attribute__((address_space(1))) void*)(g),                        \
    (__attribute__((address_space(3))) void*)(l), 16, 0, 0)

static __device__ __forceinline__ unsigned short f2bf(float f) {
    unsigned int u = __builtin_bit_cast(unsigned int, f);
    unsigned int r = u + 0x7fffu + ((u >> 16) & 1u);
    return (unsigned short)(r >> 16);
}

// ---------------- fp32 -> bf16 convert ----------------
__global__ void cvt_f32_bf16(const float* __restrict__ in, unsigned short* __restrict__ out, int n) {
    int i = (blockIdx.x * blockDim.x + threadIdx.x) * 4;
    if (i >= n) return;
    float4 v = *reinterpret_cast<const float4*>(in + i);
    ushort4 o;
    o.x = f2bf(v.x); o.y = f2bf(v.y); o.z = f2bf(v.z); o.w = f2bf(v.w);
    *reinterpret_cast<ushort4*>(out + i) = o;
}

// ---------------- QKV projection GEMM (m97-style 128x128, BK=64) ----------------
// A: hs_bf [8192][1024] row-major. W (z-selected): [N=1024][K=1024] row-major = B^T.
// out: z=0 Q [B,H,S,HD]; z=1 K [B,H,S,HD]; z=2 V^T [B,H,HD,S]  (all bf16)
// LDS tiles are stored with XOR-swizzle: logical 8-elem chunk j of row r lives at
// physical chunk j ^ (r&7). global_load_lds writes linearly, so the global SOURCE
// address is pre-swizzled (rule 21 / m173).
__global__ __launch_bounds__(256) void qkv_gemm(
    const unsigned short* __restrict__ A,
    const unsigned short* __restrict__ Wq, const unsigned short* __restrict__ Wk,
    const unsigned short* __restrict__ Wv,
    const float* __restrict__ bq, const float* __restrict__ bk, const float* __restrict__ bv,
    unsigned short* __restrict__ Qo, unsigned short* __restrict__ Ko, unsigned short* __restrict__ Vo)
{
    const int z = blockIdx.z;
    const unsigned short* W = (z == 0) ? Wq : (z == 1) ? Wk : Wv;
    const float* bias = (z == 0) ? bq : (z == 1) ? bk : bv;
    const int m0 = blockIdx.x * 128;
    const int n0 = blockIdx.y * 128;

    __shared__ unsigned short As[128][64];   // 16 KB, swizzled
    __shared__ unsigned short Bs[128][64];   // 16 KB, swizzled

    const int tid = threadIdx.x;
    const int lane = tid & 63;
    const int wave = tid >> 6;
    const int wm = wave >> 1, wn = wave & 1;

    f32x4 acc[4][4] = {};

    // staging geometry: 1 KB chunk = 8 rows x 64B half... (8 rows x 128B = 1KB)
    const int crow = lane >> 3;                    // row within chunk 0..7
    const int gcol = ((lane & 7) ^ crow) * 8;      // pre-swizzled source col (elems)
    const int kofs = (lane >> 4) * 8;

    for (int kb = 0; kb < ND; kb += 64) {
#pragma unroll
        for (int cc = 0; cc < 4; ++cc) {
            int c = wave * 4 + cc;                 // 16 chunks each
            GLOAD_LDS16(&A[(size_t)(m0 + c * 8 + crow) * ND + kb + gcol], &As[c * 8][0]);
            GLOAD_LDS16(&W[(size_t)(n0 + c * 8 + crow) * ND + kb + gcol], &Bs[c * 8][0]);
        }
        __syncthreads();
#pragma unroll
        for (int kk = 0; kk < 2; ++kk) {
            const int colx = (kk * 32 + kofs) ^ ((lane & 7) * 8);
            bf16x8 af[4], bfr[4];
#pragma unroll
            for (int i = 0; i < 4; ++i) {
                af[i]  = *reinterpret_cast<const bf16x8*>(&As[wm * 64 + i * 16 + (lane & 15)][colx]);
                bfr[i] = *reinterpret_cast<const bf16x8*>(&Bs[wn * 64 + i * 16 + (lane & 15)][colx]);
            }
#pragma unroll
            for (int mi = 0; mi < 4; ++mi)
#pragma unroll
                for (int ni = 0; ni < 4; ++ni)
                    acc[mi][ni] = __builtin_amdgcn_mfma_f32_16x16x32_bf16(af[mi], bfr[ni], acc[mi][ni], 0, 0, 0);
        }
        __syncthreads();
    }

    // C layout: col = lane&15 (n), row = (lane>>4)*4 + r (m)
#pragma unroll
    for (int ni = 0; ni < 4; ++ni) {
        int n = n0 + wn * 64 + ni * 16 + (lane & 15);
        float bv_ = bias[n];
        int h = n >> 6, hd = n & 63;
#pragma unroll
        for (int mi = 0; mi < 4; ++mi) {
            int m = m0 + wm * 64 + mi * 16 + (lane >> 4) * 4;
            int b = m >> 10, s = m & 1023;
            if (z == 2) {
                ushort4 o;
                o.x = f2bf(acc[mi][ni][0] + bv_);
                o.y = f2bf(acc[mi][ni][1] + bv_);
                o.z = f2bf(acc[mi][ni][2] + bv_);
                o.w = f2bf(acc[mi][ni][3] + bv_);
                *reinterpret_cast<ushort4*>(&Vo[(((size_t)b * NH + h) * NHD + hd) * NS + s]) = o;
            } else {
                unsigned short* O = (z == 0) ? Qo : Ko;
#pragma unroll
                for (int r2 = 0; r2 < 4; ++r2)
                    O[(((size_t)b * NH + h) * NS + s + r2) * NHD + hd] = f2bf(acc[mi][ni][r2] + bv_);
            }
        }
    }
}

// ---------------- flash attention with relation bias ----------------
// grid: (S/64, H, B), block 256 (4 waves). Each wave owns 16 q-rows.
// Ks/Vs/Ps use the same XOR chunk-swizzle; K/V staged via global_load_lds with
// pre-swizzled global source.
__global__ __launch_bounds__(256) void flash_attn(
    const unsigned short* __restrict__ Q, const unsigned short* __restrict__ Kb,
    const unsigned short* __restrict__ Vt,
    const int* __restrict__ rel, const float* __restrict__ rel_emb,
    const float* __restrict__ mask, float* __restrict__ out)
{
    const int q0 = blockIdx.x * 64;
    const int h = blockIdx.y;
    const int b = blockIdx.z;
    const int tid = threadIdx.x, lane = tid & 63, wave = tid >> 6;

    __shared__ unsigned short Ks[64][64];   // [kv][hd], swizzled
    __shared__ unsigned short Vs[64][64];   // [hd][kv], swizzled
    __shared__ unsigned short Ps[4][16][64];// per-wave, swizzled
    __shared__ float s_re[8];
    if (tid < 7) s_re[tid] = rel_emb[tid * NH + h];

    const unsigned short* Qh = Q  + (((size_t)b * NH + h) * NS) * NHD;
    const unsigned short* Kh = Kb + (((size_t)b * NH + h) * NS) * NHD;
    const unsigned short* Vh = Vt + (((size_t)b * NH + h) * NHD) * NS;
    const int* relb = rel + (size_t)b * NS * NS;
    const float* maskb = mask + (size_t)b * NS;

    const int kofs = (lane >> 4) * 8;
    const int qrow = q0 + wave * 16 + (lane & 15);
    bf16x8 qa[2];
    qa[0] = *reinterpret_cast<const bf16x8*>(&Qh[(size_t)qrow * NHD + kofs]);
    qa[1] = *reinterpret_cast<const bf16x8*>(&Qh[(size_t)qrow * NHD + 32 + kofs]);

    f32x4 ctx[4] = {};
    float m_run[4], l_run[4];
#pragma unroll
    for (int r = 0; r < 4; ++r) { m_run[r] = -1e30f; l_run[r] = 0.f; }

    const int crow = lane >> 3;                   // staging row-in-chunk
    const int gcol = ((lane & 7) ^ crow) * 8;     // pre-swizzled source col
    const int swz = (lane & 7) * 8;               // fragment-read col XOR
    const float LOG2E = 1.4426950408889634f;

    for (int kv0 = 0; kv0 < NS; kv0 += 64) {
#pragma unroll
        for (int cc = 0; cc < 2; ++cc) {
            int c = wave * 2 + cc;                // 8 chunks each for Ks, Vs
            GLOAD_LDS16(&Kh[(size_t)(kv0 + c * 8 + crow) * NHD + gcol], &Ks[c * 8][0]);
            GLOAD_LDS16(&Vh[(size_t)(c * 8 + crow) * NS + kv0 + gcol], &Vs[c * 8][0]);
        }
        __syncthreads();

        // scores = Q K^T  (C: col=kv local, row=q local)
        f32x4 sc[4] = {};
#pragma unroll
        for (int kk = 0; kk < 2; ++kk) {
            const int colx = (kk * 32 + kofs) ^ swz;
#pragma unroll
            for (int nt = 0; nt < 4; ++nt) {
                bf16x8 bfrag = *reinterpret_cast<const bf16x8*>(&Ks[nt * 16 + (lane & 15)][colx]);
                sc[nt] = __builtin_amdgcn_mfma_f32_16x16x32_bf16(qa[kk], bfrag, sc[nt], 0, 0, 0);
            }
        }

        // scale + relation bias + mask, track per-row max
        float svals[4][4];
        float pmax[4];
#pragma unroll
        for (int r = 0; r < 4; ++r) pmax[r] = -1e30f;
#pragma unroll
        for (int nt = 0; nt < 4; ++nt) {
            int kvg = kv0 + nt * 16 + (lane & 15);
            float mv = maskb[kvg];
#pragma unroll
            for (int r = 0; r < 4; ++r) {
                int qg = q0 + wave * 16 + (lane >> 4) * 4 + r;
                int rc = relb[(size_t)qg * NS + kvg];
                float sv = sc[nt][r] * 0.125f + s_re[rc] + mv;
                svals[nt][r] = sv;
                pmax[r] = fmaxf(pmax[r], sv);
            }
        }
#pragma unroll
        for (int r = 0; r < 4; ++r) {
            float v = pmax[r];
            v = fmaxf(v, __shfl_xor(v, 1));
            v = fmaxf(v, __shfl_xor(v, 2));
            v = fmaxf(v, __shfl_xor(v, 4));
            v = fmaxf(v, __shfl_xor(v, 8));
            pmax[r] = v;
        }
        float alpha[4], rsum[4];
#pragma unroll
        for (int r = 0; r < 4; ++r) {
            float mnew = fmaxf(m_run[r], pmax[r]);
            alpha[r] = exp2f((m_run[r] - mnew) * LOG2E);
            m_run[r] = mnew;
            rsum[r] = 0.f;
        }
#pragma unroll
        for (int nt = 0; nt < 4; ++nt) {
#pragma unroll
            for (int r = 0; r < 4; ++r) {
                float p = exp2f((svals[nt][r] - m_run[r]) * LOG2E);
                rsum[r] += p;
                int pr = (lane >> 4) * 4 + r;
                Ps[wave][pr][(nt * 16 + (lane & 15)) ^ ((pr & 7) * 8)] = f2bf(p);
            }
        }
#pragma unroll
        for (int r = 0; r < 4; ++r) {
            float v = rsum[r];
            v += __shfl_xor(v, 1);
            v += __shfl_xor(v, 2);
            v += __shfl_xor(v, 4);
            v += __shfl_xor(v, 8);
            l_run[r] = l_run[r] * alpha[r] + v;
        }
#pragma unroll
        for (int ht = 0; ht < 4; ++ht)
#pragma unroll
            for (int r = 0; r < 4; ++r)
                ctx[ht][r] *= alpha[r];

        // ctx += P V   (A from Ps, B from Vs)
#pragma unroll
        for (int kk = 0; kk < 2; ++kk) {
            const int colx = (kk * 32 + kofs) ^ swz;
            bf16x8 pa = *reinterpret_cast<const bf16x8*>(&Ps[wave][lane & 15][colx]);
#pragma unroll
            for (int ht = 0; ht < 4; ++ht) {
                bf16x8 bfrag = *reinterpret_cast<const bf16x8*>(&Vs[ht * 16 + (lane & 15)][colx]);
                ctx[ht] = __builtin_amdgcn_mfma_f32_16x16x32_bf16(pa, bfrag, ctx[ht], 0, 0, 0);
            }
        }
        __syncthreads();
    }

    // epilogue: out[b][q][h*64+hd] = ctx / l
#pragma unroll
    for (int ht = 0; ht < 4; ++ht) {
        int hd = ht * 16 + (lane & 15);
#pragma unroll
        for (int r = 0; r < 4; ++r) {
            int qg = q0 + wave * 16 + (lane >> 4) * 4 + r;
            out[((size_t)b * NS + qg) * ND + h * NHD + hd] = ctx[ht][r] / l_run[r];
        }
    }
}

extern "C" void kernel_launch(void* const* d_in, const int* in_sizes, int n_in,
                              void* d_out, int out_size, void* d_ws, size_t ws_size,
                              hipStream_t stream) {
    const float* hs      = (const float*)d_in[0];
    const float* mask    = (const float*)d_in[1];
    const int*   rel     = (const int*)d_in[2];
    const float* Wq      = (const float*)d_in[3];
    const float* bq      = (const float*)d_in[4];
    const float* Wk      = (const float*)d_in[5];
    const float* bk      = (const float*)d_in[6];
    const float* Wv      = (const float*)d_in[7];
    const float* bv      = (const float*)d_in[8];
    const float* rel_emb = (const float*)d_in[9];
    float* out = (float*)d_out;

    char* ws = (char*)d_ws;
    unsigned short* q_bf  = (unsigned short*)(ws);                       // 16 MB
    unsigned short* k_bf  = (unsigned short*)(ws + ((size_t)16 << 20));  // 16 MB
    unsigned short* vt_bf = (unsigned short*)(ws + ((size_t)32 << 20));  // 16 MB
    unsigned short* hs_bf = (unsigned short*)(ws + ((size_t)48 << 20));  // 16 MB
    unsigned short* w_bf  = (unsigned short*)(ws + ((size_t)64 << 20));  // 6 MB

    const int nhs = NB * NS * ND;       // 8.4M
    const int nw  = ND * ND;            // 1M
    cvt_f32_bf16<<<nhs / 4 / 256, 256, 0, stream>>>(hs, hs_bf, nhs);
    cvt_f32_bf16<<<nw / 4 / 256, 256, 0, stream>>>(Wq, w_bf, nw);
    cvt_f32_bf16<<<nw / 4 / 256, 256, 0, stream>>>(Wk, w_bf + (size_t)nw, nw);
    cvt_f32_bf16<<<nw / 4 / 256, 256, 0, stream>>>(Wv, w_bf + (size_t)2 * nw, nw);

    qkv_gemm<<<dim3((NB * NS) / 128, ND / 128, 3), 256, 0, stream>>>(
        hs_bf, w_bf, w_bf + (size_t)nw, w_bf + (size_t)2 * nw,
        bq, bk, bv, q_bf, k_bf, vt_bf);

    flash_attn<<<dim3(NS / 64, NH, NB), 256, 0, stream>>>(
        q_bf, k_bf, vt_bf, rel, rel_emb, mask, out);
}

// Round 4
// 202.262 us; speedup vs baseline: 1.6081x; 1.1319x over previous
//
#include <hip/hip_runtime.h>

#define NB 8
#define NS 1024
#define ND 1024
#define NH 16
#define NHD 64

typedef __attribute__((ext_vector_type(8))) short bf16x8;
typedef __attribute__((ext_vector_type(4))) float f32x4;

#define GLOAD_LDS16(g, l) __builtin_amdgcn_global_load_lds(                    \
    (const __attribute__((address_space(1))) void*)(g),                        \
    (__attribute__((address_space(3))) void*)(l), 16, 0, 0)

static __device__ __forceinline__ unsigned short f2bf(float f) {
    unsigned int u = __builtin_bit_cast(unsigned int, f);
    unsigned int r = u + 0x7fffu + ((u >> 16) & 1u);
    return (unsigned short)(r >> 16);
}

static __device__ __forceinline__ unsigned int pkbf2(float lo, float hi) {
    return ((unsigned int)f2bf(hi) << 16) | (unsigned int)f2bf(lo);
}

// ---------------- fp32 -> bf16 convert ----------------
__global__ void cvt_f32_bf16(const float* __restrict__ in, unsigned short* __restrict__ out, int n) {
    int i = (blockIdx.x * blockDim.x + threadIdx.x) * 4;
    if (i >= n) return;
    float4 v = *reinterpret_cast<const float4*>(in + i);
    ushort4 o;
    o.x = f2bf(v.x); o.y = f2bf(v.y); o.z = f2bf(v.z); o.w = f2bf(v.w);
    *reinterpret_cast<ushort4*>(out + i) = o;
}

// ---------------- QKV projection GEMM (m97-style 128x128, BK=64) ----------------
__global__ __launch_bounds__(256) void qkv_gemm(
    const unsigned short* __restrict__ A,
    const unsigned short* __restrict__ Wq, const unsigned short* __restrict__ Wk,
    const unsigned short* __restrict__ Wv,
    const float* __restrict__ bq, const float* __restrict__ bk, const float* __restrict__ bv,
    unsigned short* __restrict__ Qo, unsigned short* __restrict__ Ko, unsigned short* __restrict__ Vo)
{
    const int z = blockIdx.z;
    const unsigned short* W = (z == 0) ? Wq : (z == 1) ? Wk : Wv;
    const float* bias = (z == 0) ? bq : (z == 1) ? bk : bv;
    const int m0 = blockIdx.x * 128;
    const int n0 = blockIdx.y * 128;

    __shared__ unsigned short As[128][64];   // 16 KB, swizzled
    __shared__ unsigned short Bs[128][64];   // 16 KB, swizzled

    const int tid = threadIdx.x;
    const int lane = tid & 63;
    const int wave = tid >> 6;
    const int wm = wave >> 1, wn = wave & 1;

    f32x4 acc[4][4] = {};

    const int crow = lane >> 3;                    // row within chunk 0..7
    const int gcol = ((lane & 7) ^ crow) * 8;      // pre-swizzled source col (elems)
    const int kofs = (lane >> 4) * 8;

    for (int kb = 0; kb < ND; kb += 64) {
#pragma unroll
        for (int cc = 0; cc < 4; ++cc) {
            int c = wave * 4 + cc;                 // 16 chunks each
            GLOAD_LDS16(&A[(size_t)(m0 + c * 8 + crow) * ND + kb + gcol], &As[c * 8][0]);
            GLOAD_LDS16(&W[(size_t)(n0 + c * 8 + crow) * ND + kb + gcol], &Bs[c * 8][0]);
        }
        __syncthreads();
#pragma unroll
        for (int kk = 0; kk < 2; ++kk) {
            const int colx = (kk * 32 + kofs) ^ ((lane & 7) * 8);
            bf16x8 af[4], bfr[4];
#pragma unroll
            for (int i = 0; i < 4; ++i) {
                af[i]  = *reinterpret_cast<const bf16x8*>(&As[wm * 64 + i * 16 + (lane & 15)][colx]);
                bfr[i] = *reinterpret_cast<const bf16x8*>(&Bs[wn * 64 + i * 16 + (lane & 15)][colx]);
            }
#pragma unroll
            for (int mi = 0; mi < 4; ++mi)
#pragma unroll
                for (int ni = 0; ni < 4; ++ni)
                    acc[mi][ni] = __builtin_amdgcn_mfma_f32_16x16x32_bf16(af[mi], bfr[ni], acc[mi][ni], 0, 0, 0);
        }
        __syncthreads();
    }

#pragma unroll
    for (int ni = 0; ni < 4; ++ni) {
        int n = n0 + wn * 64 + ni * 16 + (lane & 15);
        float bv_ = bias[n];
        int h = n >> 6, hd = n & 63;
#pragma unroll
        for (int mi = 0; mi < 4; ++mi) {
            int m = m0 + wm * 64 + mi * 16 + (lane >> 4) * 4;
            int b = m >> 10, s = m & 1023;
            if (z == 2) {
                ushort4 o;
                o.x = f2bf(acc[mi][ni][0] + bv_);
                o.y = f2bf(acc[mi][ni][1] + bv_);
                o.z = f2bf(acc[mi][ni][2] + bv_);
                o.w = f2bf(acc[mi][ni][3] + bv_);
                *reinterpret_cast<ushort4*>(&Vo[(((size_t)b * NH + h) * NHD + hd) * NS + s]) = o;
            } else {
                unsigned short* O = (z == 0) ? Qo : Ko;
#pragma unroll
                for (int r2 = 0; r2 < 4; ++r2)
                    O[(((size_t)b * NH + h) * NS + s + r2) * NHD + hd] = f2bf(acc[mi][ni][r2] + bv_);
            }
        }
    }
}

// ---------------- flash attention, swapped-QK^T structure ----------------
// grid: (S/64, H, B), block 256 (4 waves). Wave owns q-rows [wave*16, +16).
// QK^T computed as mfma(K, Q) -> S^T tiles: lane&15 = q, regs = kv.
// Softmax state (m, l) is scalar per lane (one q-row per lane).
__global__ __launch_bounds__(256) void flash_attn(
    const unsigned short* __restrict__ Q, const unsigned short* __restrict__ Kb,
    const unsigned short* __restrict__ Vt,
    const int* __restrict__ rel, const float* __restrict__ rel_emb,
    const float* __restrict__ mask, float* __restrict__ out)
{
    const int q0 = blockIdx.x * 64;
    const int h = blockIdx.y;
    const int b = blockIdx.z;
    const int tid = threadIdx.x, lane = tid & 63, wave = tid >> 6;
    const int g = lane >> 4, l15 = lane & 15;

    __shared__ unsigned short Ks[64][64];    // [kv][hd], chunk-swizzled
    __shared__ unsigned short Vs[64][64];    // [hd][kv], chunk-swizzled
    __shared__ unsigned short Ps[4][16][64]; // per-wave [q][kv], chunk-swizzled
    __shared__ float s_re2[8];               // rel_emb[.][h] * log2(e)
    const float LOG2E = 1.4426950408889634f;
    const float SCL2 = 0.125f * 1.4426950408889634f;
    if (tid < 7) s_re2[tid] = rel_emb[tid * NH + h] * LOG2E;

    const unsigned short* Qh = Q  + (((size_t)b * NH + h) * NS) * NHD;
    const unsigned short* Kh = Kb + (((size_t)b * NH + h) * NS) * NHD;
    const unsigned short* Vh = Vt + (((size_t)b * NH + h) * NHD) * NS;
    const int qg = q0 + wave * 16 + l15;                 // this lane's q-row
    const int* __restrict__ relrow = rel + (size_t)b * NS * NS + (size_t)qg * NS;
    const float* __restrict__ maskb = mask + (size_t)b * NS;

    bf16x8 qa[2];
    qa[0] = *reinterpret_cast<const bf16x8*>(&Qh[(size_t)qg * NHD + g * 8]);
    qa[1] = *reinterpret_cast<const bf16x8*>(&Qh[(size_t)qg * NHD + 32 + g * 8]);

    f32x4 ctx[4] = {};
    float m2 = -1e30f, l_run = 0.f;

    const int crow = lane >> 3;
    const int gcol = ((lane & 7) ^ crow) * 8;
    const int swz8 = (lane & 7) * 8;          // == (l15&7)*8

    for (int kv0 = 0; kv0 < NS; kv0 += 64) {
#pragma unroll
        for (int cc = 0; cc < 2; ++cc) {
            int c = wave * 2 + cc;
            GLOAD_LDS16(&Kh[(size_t)(kv0 + c * 8 + crow) * NHD + gcol], &Ks[c * 8][0]);
            GLOAD_LDS16(&Vh[(size_t)(c * 8 + crow) * NS + kv0 + gcol], &Vs[c * 8][0]);
        }
        __syncthreads();

        // S^T = K Q^T : C tiles have col=q (lane&15), row=kv (g*4+r)
        f32x4 sc[4] = {};
#pragma unroll
        for (int kk = 0; kk < 2; ++kk) {
            const int colx = (kk * 32 + g * 8) ^ swz8;
#pragma unroll
            for (int nt = 0; nt < 4; ++nt) {
                bf16x8 kfrag = *reinterpret_cast<const bf16x8*>(&Ks[nt * 16 + l15][colx]);
                sc[nt] = __builtin_amdgcn_mfma_f32_16x16x32_bf16(kfrag, qa[kk], sc[nt], 0, 0, 0);
            }
        }

        // bias (log2 domain) + per-row max; kv of sc[nt][r] = kv0 + nt*16 + 4g + r
        float pmax = -1e30f;
#pragma unroll
        for (int nt = 0; nt < 4; ++nt) {
            int4 rc4 = *reinterpret_cast<const int4*>(&relrow[kv0 + nt * 16 + 4 * g]);
            float4 mv4 = *reinterpret_cast<const float4*>(&maskb[kv0 + nt * 16 + 4 * g]);
            const int rca[4] = {rc4.x, rc4.y, rc4.z, rc4.w};
            const float mva[4] = {mv4.x, mv4.y, mv4.z, mv4.w};
#pragma unroll
            for (int r = 0; r < 4; ++r) {
                float bias2 = fmaf(mva[r], LOG2E, s_re2[rca[r]]);
                float v = fmaf(sc[nt][r], SCL2, bias2);
                sc[nt][r] = v;
                pmax = fmaxf(pmax, v);
            }
        }
        pmax = fmaxf(pmax, __shfl_xor(pmax, 16));
        pmax = fmaxf(pmax, __shfl_xor(pmax, 32));

        float mnew = fmaxf(m2, pmax);
        float alpha = exp2f(m2 - mnew);
        m2 = mnew;

        float rsum = 0.f;
#pragma unroll
        for (int nt = 0; nt < 4; ++nt) {
            float p0 = exp2f(sc[nt][0] - m2);
            float p1 = exp2f(sc[nt][1] - m2);
            float p2 = exp2f(sc[nt][2] - m2);
            float p3 = exp2f(sc[nt][3] - m2);
            rsum += (p0 + p1) + (p2 + p3);
            int pc = (2 * nt + (g >> 1)) ^ (l15 & 7);
            *reinterpret_cast<uint2*>(&Ps[wave][l15][pc * 8 + 4 * (g & 1)]) =
                make_uint2(pkbf2(p0, p1), pkbf2(p2, p3));
        }
        rsum += __shfl_xor(rsum, 16);
        rsum += __shfl_xor(rsum, 32);
        l_run = l_run * alpha + rsum;

        // broadcast alpha for ctx rows (ctx row = q_local = 4g + r)
        float ar[4];
#pragma unroll
        for (int r = 0; r < 4; ++r) ar[r] = __shfl(alpha, 4 * g + r);
#pragma unroll
        for (int ht = 0; ht < 4; ++ht)
#pragma unroll
            for (int r = 0; r < 4; ++r) ctx[ht][r] *= ar[r];

        // ctx += P V : A = P from Ps (row=q=l15), B = V^T from Vs (col=hd)
#pragma unroll
        for (int kk = 0; kk < 2; ++kk) {
            bf16x8 pa = *reinterpret_cast<const bf16x8*>(
                &Ps[wave][l15][((kk * 4 + g) ^ (l15 & 7)) * 8]);
            const int colx = (kk * 32 + g * 8) ^ swz8;
#pragma unroll
            for (int ht = 0; ht < 4; ++ht) {
                bf16x8 bfrag = *reinterpret_cast<const bf16x8*>(&Vs[ht * 16 + l15][colx]);
                ctx[ht] = __builtin_amdgcn_mfma_f32_16x16x32_bf16(pa, bfrag, ctx[ht], 0, 0, 0);
            }
        }
        __syncthreads();
    }

    // epilogue: ctx row = q_local = 4g + r, col = hd = ht*16 + l15
    float linv[4];
#pragma unroll
    for (int r = 0; r < 4; ++r) linv[r] = 1.0f / __shfl(l_run, 4 * g + r);
#pragma unroll
    for (int ht = 0; ht < 4; ++ht) {
        int hd = ht * 16 + l15;
#pragma unroll
        for (int r = 0; r < 4; ++r) {
            int qo = q0 + wave * 16 + 4 * g + r;
            out[((size_t)b * NS + qo) * ND + h * NHD + hd] = ctx[ht][r] * linv[r];
        }
    }
}

extern "C" void kernel_launch(void* const* d_in, const int* in_sizes, int n_in,
                              void* d_out, int out_size, void* d_ws, size_t ws_size,
                              hipStream_t stream) {
    const float* hs      = (const float*)d_in[0];
    const float* mask    = (const float*)d_in[1];
    const int*   rel     = (const int*)d_in[2];
    const float* Wq      = (const float*)d_in[3];
    const float* bq      = (const float*)d_in[4];
    const float* Wk      = (const float*)d_in[5];
    const float* bk      = (const float*)d_in[6];
    const float* Wv      = (const float*)d_in[7];
    const float* bv      = (const float*)d_in[8];
    const float* rel_emb = (const float*)d_in[9];
    float* out = (float*)d_out;

    char* ws = (char*)d_ws;
    unsigned short* q_bf  = (unsigned short*)(ws);                       // 16 MB
    unsigned short* k_bf  = (unsigned short*)(ws + ((size_t)16 << 20));  // 16 MB
    unsigned short* vt_bf = (unsigned short*)(ws + ((size_t)32 << 20));  // 16 MB
    unsigned short* hs_bf = (unsigned short*)(ws + ((size_t)48 << 20));  // 16 MB
    unsigned short* w_bf  = (unsigned short*)(ws + ((size_t)64 << 20));  // 6 MB

    const int nhs = NB * NS * ND;       // 8.4M
    const int nw  = ND * ND;            // 1M
    cvt_f32_bf16<<<nhs / 4 / 256, 256, 0, stream>>>(hs, hs_bf, nhs);
    cvt_f32_bf16<<<nw / 4 / 256, 256, 0, stream>>>(Wq, w_bf, nw);
    cvt_f32_bf16<<<nw / 4 / 256, 256, 0, stream>>>(Wk, w_bf + (size_t)nw, nw);
    cvt_f32_bf16<<<nw / 4 / 256, 256, 0, stream>>>(Wv, w_bf + (size_t)2 * nw, nw);

    qkv_gemm<<<dim3((NB * NS) / 128, ND / 128, 3), 256, 0, stream>>>(
        hs_bf, w_bf, w_bf + (size_t)nw, w_bf + (size_t)2 * nw,
        bq, bk, bv, q_bf, k_bf, vt_bf);

    flash_attn<<<dim3(NS / 64, NH, NB), 256, 0, stream>>>(
        q_bf, k_bf, vt_bf, rel, rel_emb, mask, out);
}

// Round 5
// 201.224 us; speedup vs baseline: 1.6164x; 1.0052x over previous
//
#include <hip/hip_runtime.h>

#define NB 8
#define NS 1024
#define ND 1024
#define NH 16
#define NHD 64

typedef __attribute__((ext_vector_type(8))) short bf16x8;
typedef __attribute__((ext_vector_type(4))) float f32x4;

#define GLOAD_LDS16(g, l) __builtin_amdgcn_global_load_lds(                    \
    (const __attribute__((address_space(1))) void*)(g),                        \
    (__attribute__((address_space(3))) void*)(l), 16, 0, 0)

static __device__ __forceinline__ unsigned short f2bf(float f) {
    unsigned int u = __builtin_bit_cast(unsigned int, f);
    unsigned int r = u + 0x7fffu + ((u >> 16) & 1u);
    return (unsigned short)(r >> 16);
}

static __device__ __forceinline__ unsigned int cvtpk(float lo, float hi) {
    unsigned int r;
    asm("v_cvt_pk_bf16_f32 %0, %1, %2" : "=v"(r) : "v"(lo), "v"(hi));
    return r;
}

// ---------------- fp32 -> bf16 convert ----------------
__global__ void cvt_f32_bf16(const float* __restrict__ in, unsigned short* __restrict__ out, int n) {
    int i = (blockIdx.x * blockDim.x + threadIdx.x) * 4;
    if (i >= n) return;
    float4 v = *reinterpret_cast<const float4*>(in + i);
    ushort4 o;
    o.x = f2bf(v.x); o.y = f2bf(v.y); o.z = f2bf(v.z); o.w = f2bf(v.w);
    *reinterpret_cast<ushort4*>(out + i) = o;
}

// ---------------- QKV projection GEMM (m97-style 128x128, BK=64) ----------------
__global__ __launch_bounds__(256) void qkv_gemm(
    const unsigned short* __restrict__ A,
    const unsigned short* __restrict__ Wq, const unsigned short* __restrict__ Wk,
    const unsigned short* __restrict__ Wv,
    const float* __restrict__ bq, const float* __restrict__ bk, const float* __restrict__ bv,
    unsigned short* __restrict__ Qo, unsigned short* __restrict__ Ko, unsigned short* __restrict__ Vo)
{
    const int z = blockIdx.z;
    const unsigned short* W = (z == 0) ? Wq : (z == 1) ? Wk : Wv;
    const float* bias = (z == 0) ? bq : (z == 1) ? bk : bv;
    const int m0 = blockIdx.x * 128;
    const int n0 = blockIdx.y * 128;

    __shared__ unsigned short As[128][64];   // 16 KB, swizzled
    __shared__ unsigned short Bs[128][64];   // 16 KB, swizzled

    const int tid = threadIdx.x;
    const int lane = tid & 63;
    const int wave = tid >> 6;
    const int wm = wave >> 1, wn = wave & 1;

    f32x4 acc[4][4] = {};

    const int crow = lane >> 3;                    // row within chunk 0..7
    const int gcol = ((lane & 7) ^ crow) * 8;      // pre-swizzled source col (elems)
    const int kofs = (lane >> 4) * 8;

    for (int kb = 0; kb < ND; kb += 64) {
#pragma unroll
        for (int cc = 0; cc < 4; ++cc) {
            int c = wave * 4 + cc;                 // 16 chunks each
            GLOAD_LDS16(&A[(size_t)(m0 + c * 8 + crow) * ND + kb + gcol], &As[c * 8][0]);
            GLOAD_LDS16(&W[(size_t)(n0 + c * 8 + crow) * ND + kb + gcol], &Bs[c * 8][0]);
        }
        __syncthreads();
#pragma unroll
        for (int kk = 0; kk < 2; ++kk) {
            const int colx = (kk * 32 + kofs) ^ ((lane & 7) * 8);
            bf16x8 af[4], bfr[4];
#pragma unroll
            for (int i = 0; i < 4; ++i) {
                af[i]  = *reinterpret_cast<const bf16x8*>(&As[wm * 64 + i * 16 + (lane & 15)][colx]);
                bfr[i] = *reinterpret_cast<const bf16x8*>(&Bs[wn * 64 + i * 16 + (lane & 15)][colx]);
            }
#pragma unroll
            for (int mi = 0; mi < 4; ++mi)
#pragma unroll
                for (int ni = 0; ni < 4; ++ni)
                    acc[mi][ni] = __builtin_amdgcn_mfma_f32_16x16x32_bf16(af[mi], bfr[ni], acc[mi][ni], 0, 0, 0);
        }
        __syncthreads();
    }

#pragma unroll
    for (int ni = 0; ni < 4; ++ni) {
        int n = n0 + wn * 64 + ni * 16 + (lane & 15);
        float bv_ = bias[n];
        int h = n >> 6, hd = n & 63;
#pragma unroll
        for (int mi = 0; mi < 4; ++mi) {
            int m = m0 + wm * 64 + mi * 16 + (lane >> 4) * 4;
            int b = m >> 10, s = m & 1023;
            if (z == 2) {
                ushort4 o;
                o.x = f2bf(acc[mi][ni][0] + bv_);
                o.y = f2bf(acc[mi][ni][1] + bv_);
                o.z = f2bf(acc[mi][ni][2] + bv_);
                o.w = f2bf(acc[mi][ni][3] + bv_);
                *reinterpret_cast<ushort4*>(&Vo[(((size_t)b * NH + h) * NHD + hd) * NS + s]) = o;
            } else {
                unsigned short* O = (z == 0) ? Qo : Ko;
#pragma unroll
                for (int r2 = 0; r2 < 4; ++r2)
                    O[(((size_t)b * NH + h) * NS + s + r2) * NHD + hd] = f2bf(acc[mi][ni][r2] + bv_);
            }
        }
    }
}

// ---------------- flash attention, swapped-QK^T + dbuf K/V + defer-max ----------------
// grid: (S/64, H, B), block 256 (4 waves). Wave owns q-rows [wave*16, +16).
// QK^T computed as mfma(K, Q) -> S^T tiles: lane&15 = q, regs = kv.
__global__ __launch_bounds__(256) void flash_attn(
    const unsigned short* __restrict__ Q, const unsigned short* __restrict__ Kb,
    const unsigned short* __restrict__ Vt,
    const int* __restrict__ rel, const float* __restrict__ rel_emb,
    const float* __restrict__ mask, float* __restrict__ out)
{
    const int q0 = blockIdx.x * 64;
    const int h = blockIdx.y;
    const int b = blockIdx.z;
    const int tid = threadIdx.x, lane = tid & 63, wave = tid >> 6;
    const int g = lane >> 4, l15 = lane & 15;

    __shared__ unsigned short Ks[2][64][64]; // [buf][kv][hd], chunk-swizzled
    __shared__ unsigned short Vs[2][64][64]; // [buf][hd][kv], chunk-swizzled
    __shared__ unsigned short Ps[4][16][64]; // per-wave [q][kv], chunk-swizzled
    __shared__ float s_re2[8];               // rel_emb[.][h] * log2(e)
    const float LOG2E = 1.4426950408889634f;
    const float SCL2 = 0.125f * 1.4426950408889634f;
    if (tid < 7) s_re2[tid] = rel_emb[tid * NH + h] * LOG2E;

    const unsigned short* Qh = Q  + (((size_t)b * NH + h) * NS) * NHD;
    const unsigned short* Kh = Kb + (((size_t)b * NH + h) * NS) * NHD;
    const unsigned short* Vh = Vt + (((size_t)b * NH + h) * NHD) * NS;
    const int qg = q0 + wave * 16 + l15;                 // this lane's q-row
    const int* __restrict__ relrow = rel + (size_t)b * NS * NS + (size_t)qg * NS;
    const float* __restrict__ maskb = mask + (size_t)b * NS;

    bf16x8 qa[2];
    qa[0] = *reinterpret_cast<const bf16x8*>(&Qh[(size_t)qg * NHD + g * 8]);
    qa[1] = *reinterpret_cast<const bf16x8*>(&Qh[(size_t)qg * NHD + 32 + g * 8]);

    f32x4 ctx[4] = {};
    float m2 = -1e30f, l_run = 0.f;

    const int crow = lane >> 3;
    const int gcol = ((lane & 7) ^ crow) * 8;
    const int swz8 = (lane & 7) * 8;          // == (l15&7)*8

#define STAGE(buf, kv)                                                                         \
    {                                                                                          \
        _Pragma("unroll")                                                                      \
        for (int cc = 0; cc < 2; ++cc) {                                                       \
            int c = wave * 2 + cc;                                                             \
            GLOAD_LDS16(&Kh[(size_t)((kv) + c * 8 + crow) * NHD + gcol], &Ks[buf][c * 8][0]);  \
            GLOAD_LDS16(&Vh[(size_t)(c * 8 + crow) * NS + (kv) + gcol], &Vs[buf][c * 8][0]);   \
        }                                                                                      \
    }

    STAGE(0, 0);
    __syncthreads();

    for (int t = 0; t < 16; ++t) {
        const int cur = t & 1;
        const int kv0 = t * 64;

        // early VMEM: relation codes + mask for this tile (consumed after QK^T)
        int4 rc4[4];
        float4 mv4[4];
#pragma unroll
        for (int nt = 0; nt < 4; ++nt) {
            rc4[nt] = *reinterpret_cast<const int4*>(&relrow[kv0 + nt * 16 + 4 * g]);
            mv4[nt] = *reinterpret_cast<const float4*>(&maskb[kv0 + nt * 16 + 4 * g]);
        }
        // prefetch next K/V tile into the other buffer (drained at this tile's barrier)
        if (t < 15) STAGE(cur ^ 1, kv0 + 64);

        // S^T = K Q^T : C tiles have col=q (lane&15), row=kv (g*4+r)
        f32x4 sc[4] = {};
        __builtin_amdgcn_s_setprio(1);
#pragma unroll
        for (int kk = 0; kk < 2; ++kk) {
            const int colx = (kk * 32 + g * 8) ^ swz8;
#pragma unroll
            for (int nt = 0; nt < 4; ++nt) {
                bf16x8 kfrag = *reinterpret_cast<const bf16x8*>(&Ks[cur][nt * 16 + l15][colx]);
                sc[nt] = __builtin_amdgcn_mfma_f32_16x16x32_bf16(kfrag, qa[kk], sc[nt], 0, 0, 0);
            }
        }
        __builtin_amdgcn_s_setprio(0);

        // bias (log2 domain) + per-row max; kv of sc[nt][r] = kv0 + nt*16 + 4g + r
        float pmax = -1e30f;
#pragma unroll
        for (int nt = 0; nt < 4; ++nt) {
            const int rca[4] = {rc4[nt].x, rc4[nt].y, rc4[nt].z, rc4[nt].w};
            const float mva[4] = {mv4[nt].x, mv4[nt].y, mv4[nt].z, mv4[nt].w};
#pragma unroll
            for (int r = 0; r < 4; ++r) {
                float bias2 = fmaf(mva[r], LOG2E, s_re2[rca[r]]);
                float v = fmaf(sc[nt][r], SCL2, bias2);
                sc[nt][r] = v;
                pmax = fmaxf(pmax, v);
            }
        }
        pmax = fmaxf(pmax, __shfl_xor(pmax, 16));
        pmax = fmaxf(pmax, __shfl_xor(pmax, 32));

        // defer-max (T13): only rescale when the running max grew materially
        if (!__all(pmax - m2 <= 8.0f)) {
            float mnew = fmaxf(m2, pmax);
            float alpha = exp2f(m2 - mnew);
            m2 = mnew;
            l_run *= alpha;
            float ar[4];
#pragma unroll
            for (int r = 0; r < 4; ++r) ar[r] = __shfl(alpha, 4 * g + r);
#pragma unroll
            for (int ht = 0; ht < 4; ++ht)
#pragma unroll
                for (int r = 0; r < 4; ++r) ctx[ht][r] *= ar[r];
        }

        float rsum = 0.f;
#pragma unroll
        for (int nt = 0; nt < 4; ++nt) {
            float p0 = exp2f(sc[nt][0] - m2);
            float p1 = exp2f(sc[nt][1] - m2);
            float p2 = exp2f(sc[nt][2] - m2);
            float p3 = exp2f(sc[nt][3] - m2);
            rsum += (p0 + p1) + (p2 + p3);
            int pc = (2 * nt + (g >> 1)) ^ (l15 & 7);
            *reinterpret_cast<uint2*>(&Ps[wave][l15][pc * 8 + 4 * (g & 1)]) =
                make_uint2(cvtpk(p0, p1), cvtpk(p2, p3));
        }
        rsum += __shfl_xor(rsum, 16);
        rsum += __shfl_xor(rsum, 32);
        l_run += rsum;

        // ctx += P V : A = P from Ps (row=q=l15), B = V^T from Vs (col=hd)
        __builtin_amdgcn_s_setprio(1);
#pragma unroll
        for (int kk = 0; kk < 2; ++kk) {
            bf16x8 pa = *reinterpret_cast<const bf16x8*>(
                &Ps[wave][l15][((kk * 4 + g) ^ (l15 & 7)) * 8]);
            const int colx = (kk * 32 + g * 8) ^ swz8;
#pragma unroll
            for (int ht = 0; ht < 4; ++ht) {
                bf16x8 bfrag = *reinterpret_cast<const bf16x8*>(&Vs[cur][ht * 16 + l15][colx]);
                ctx[ht] = __builtin_amdgcn_mfma_f32_16x16x32_bf16(pa, bfrag, ctx[ht], 0, 0, 0);
            }
        }
        __builtin_amdgcn_s_setprio(0);
        __syncthreads();
    }
#undef STAGE

    // epilogue: ctx row = q_local = 4g + r, col = hd = ht*16 + l15
    float linv[4];
#pragma unroll
    for (int r = 0; r < 4; ++r) linv[r] = 1.0f / __shfl(l_run, 4 * g + r);
#pragma unroll
    for (int ht = 0; ht < 4; ++ht) {
        int hd = ht * 16 + l15;
#pragma unroll
        for (int r = 0; r < 4; ++r) {
            int qo = q0 + wave * 16 + 4 * g + r;
            out[((size_t)b * NS + qo) * ND + h * NHD + hd] = ctx[ht][r] * linv[r];
        }
    }
}

extern "C" void kernel_launch(void* const* d_in, const int* in_sizes, int n_in,
                              void* d_out, int out_size, void* d_ws, size_t ws_size,
                              hipStream_t stream) {
    const float* hs      = (const float*)d_in[0];
    const float* mask    = (const float*)d_in[1];
    const int*   rel     = (const int*)d_in[2];
    const float* Wq      = (const float*)d_in[3];
    const float* bq      = (const float*)d_in[4];
    const float* Wk      = (const float*)d_in[5];
    const float* bk      = (const float*)d_in[6];
    const float* Wv      = (const float*)d_in[7];
    const float* bv      = (const float*)d_in[8];
    const float* rel_emb = (const float*)d_in[9];
    float* out = (float*)d_out;

    char* ws = (char*)d_ws;
    unsigned short* q_bf  = (unsigned short*)(ws);                       // 16 MB
    unsigned short* k_bf  = (unsigned short*)(ws + ((size_t)16 << 20));  // 16 MB
    unsigned short* vt_bf = (unsigned short*)(ws + ((size_t)32 << 20));  // 16 MB
    unsigned short* hs_bf = (unsigned short*)(ws + ((size_t)48 << 20));  // 16 MB
    unsigned short* w_bf  = (unsigned short*)(ws + ((size_t)64 << 20));  // 6 MB

    const int nhs = NB * NS * ND;       // 8.4M
    const int nw  = ND * ND;            // 1M
    cvt_f32_bf16<<<nhs / 4 / 256, 256, 0, stream>>>(hs, hs_bf, nhs);
    cvt_f32_bf16<<<nw / 4 / 256, 256, 0, stream>>>(Wq, w_bf, nw);
    cvt_f32_bf16<<<nw / 4 / 256, 256, 0, stream>>>(Wk, w_bf + (size_t)nw, nw);
    cvt_f32_bf16<<<nw / 4 / 256, 256, 0, stream>>>(Wv, w_bf + (size_t)2 * nw, nw);

    qkv_gemm<<<dim3((NB * NS) / 128, ND / 128, 3), 256, 0, stream>>>(
        hs_bf, w_bf, w_bf + (size_t)nw, w_bf + (size_t)2 * nw,
        bq, bk, bv, q_bf, k_bf, vt_bf);

    flash_attn<<<dim3(NS / 64, NH, NB), 256, 0, stream>>>(
        q_bf, k_bf, vt_bf, rel, rel_emb, mask, out);
}